// Round 21
// baseline (201.828 us; speedup 1.0000x reference)
//
#include <hip/hip_runtime.h>
#include <hip/hip_bf16.h>
#include <math.h>

#define BB   4
#define CC   32
#define HH   120
#define WW   160
#define NH_  8
#define HD   20
#define HDP  32            // head dim padded to 32 (zeros) for K=32 MFMA
#define NN   3840          // sequence length (C*H)
#define ROWS 3840
#define NBH  32            // B * NH
#define LOG2E 1.44269504088896f

typedef float f32x4 __attribute__((ext_vector_type(4)));
typedef short s16x8 __attribute__((ext_vector_type(8)));
typedef short s16x4 __attribute__((ext_vector_type(4)));

static __device__ __forceinline__ unsigned short f2bf(float x) {
    return __builtin_bit_cast(unsigned short, __float2bfloat16(x));
}
static __device__ __forceinline__ float bf2f(unsigned short u) {
    unsigned v = ((unsigned)u) << 16;
    return __builtin_bit_cast(float, v);
}
static __device__ __forceinline__ float exp2fast(float x) {
#if defined(__has_builtin) && __has_builtin(__builtin_amdgcn_exp2f)
    return __builtin_amdgcn_exp2f(x);
#else
    float r; asm("v_exp_f32 %0, %1" : "=v"(r) : "v"(x)); return r;
#endif
}

// exp2 four lanes then pack to bf16 by TRUNCATION (validated R18-R20:
// absmax 0.0176 < 0.0306). BUILTIN-ONLY pack — perm path validated
// R5/R9-R20. Do NOT use the cvt_pk inline-asm variant (R7/R8 corruption).
static __device__ __forceinline__ s16x4 exp4_pack(f32x4 e) {
    unsigned u0 = __builtin_bit_cast(unsigned, exp2fast(e[0]));
    unsigned u1 = __builtin_bit_cast(unsigned, exp2fast(e[1]));
    unsigned u2 = __builtin_bit_cast(unsigned, exp2fast(e[2]));
    unsigned u3 = __builtin_bit_cast(unsigned, exp2fast(e[3]));
    uint2 w;
#if defined(__has_builtin) && __has_builtin(__builtin_amdgcn_perm)
    w.x = __builtin_amdgcn_perm(u1, u0, 0x07060302u);
    w.y = __builtin_amdgcn_perm(u3, u2, 0x07060302u);
#else
    w.x = (u0 >> 16) | (u1 & 0xffff0000u);
    w.y = (u2 >> 16) | (u3 & 0xffff0000u);
#endif
    return __builtin_bit_cast(s16x4, w);
}

static __device__ __forceinline__ f32x4 mfma32(s16x8 a, s16x8 b, f32x4 c) {
    return __builtin_amdgcn_mfma_f32_16x16x32_bf16(a, b, c, 0, 0, 0);
}
// concat two s16x4 into a K=32 fragment half-pair (register pairing, no ops)
static __device__ __forceinline__ s16x8 cat44(s16x4 a, s16x4 b) {
    s16x8 r;
    r[0]=a[0]; r[1]=a[1]; r[2]=a[2]; r[3]=a[3];
    r[4]=b[0]; r[5]=b[1]; r[6]=b[2]; r[7]=b[3];
    return r;
}

// ---------------- W prep: f32 -> bf16 [o][k]; Wq pre-scaled by log2(e) ----
__global__ __launch_bounds__(256)
void wprep_kernel(const float* __restrict__ Wq, const float* __restrict__ Wk,
                  const float* __restrict__ Wv,
                  unsigned short* __restrict__ wqb, unsigned short* __restrict__ wkb,
                  unsigned short* __restrict__ wvb)
{
    int i = blockIdx.x*256 + threadIdx.x;
    if (i < WW*WW) {
        wqb[i] = f2bf(Wq[i] * LOG2E);
        wkb[i] = f2bf(Wk[i]);
        wvb[i] = f2bf(Wv[i]);
    }
}

// ---------------- Projection via MFMA (no LDS), R18 regrid (unchanged) ---
__global__ __launch_bounds__(256)
void proj_mfma_kernel(const float* __restrict__ x,
                      const unsigned short* __restrict__ wqb,
                      const unsigned short* __restrict__ wkb,
                      const unsigned short* __restrict__ wvb,
                      const float* __restrict__ bq, const float* __restrict__ bk,
                      const float* __restrict__ bv,
                      unsigned short* __restrict__ qt, unsigned short* __restrict__ kt,
                      unsigned short* __restrict__ vb)
{
    const int tid  = threadIdx.x;
    const int wv   = tid >> 6;
    const int lane = tid & 63;
    const int g = lane >> 4, c = lane & 15;
    const int r0 = blockIdx.x*32 + (wv & 1)*16;   // wave's 16-row tile
    const int ch = wv >> 1;                        // col half: tiles ch*5..ch*5+4

    s16x8 A[5];
    const float* xrow = x + (size_t)(r0 + c)*WW;
    #pragma unroll
    for (int s = 0; s < 5; ++s) {
        float4 v0 = *(const float4*)(xrow + s*32 + g*8);
        float4 v1 = *(const float4*)(xrow + s*32 + g*8 + 4);
        s16x8 a;
        a[0]=(short)f2bf(v0.x); a[1]=(short)f2bf(v0.y);
        a[2]=(short)f2bf(v0.z); a[3]=(short)f2bf(v0.w);
        a[4]=(short)f2bf(v1.x); a[5]=(short)f2bf(v1.y);
        a[6]=(short)f2bf(v1.z); a[7]=(short)f2bf(v1.w);
        A[s] = a;
    }

    size_t baseqk[4], basev[4];
    #pragma unroll
    for (int rr = 0; rr < 4; ++rr) {
        int R  = r0 + g*4 + rr;
        int b  = R / ROWS;
        int r  = R % ROWS;
        int nh = r / 480;
        int rm = r % 480;
        int d  = rm / 24;
        int n1 = rm % 24;
        int bh = b*NH_ + nh;
        baseqk[rr] = ((size_t)bh*NN + n1*160)*HDP + d;
        basev[rr]  = ((size_t)bh*HD + d)*NN + n1*160;
    }

    const f32x4 zero4 = {0.f, 0.f, 0.f, 0.f};
    for (int nt = ch*5; nt < ch*5 + 5; ++nt) {
        const size_t wbase = (size_t)(nt*16 + c)*WW;
        f32x4 aq = zero4, ak = zero4, av = zero4;
        #pragma unroll
        for (int s = 0; s < 5; ++s) {
            s16x8 Bq = *(const s16x8*)(wqb + wbase + s*32 + g*8);
            aq = mfma32(A[s], Bq, aq);
            s16x8 Bk = *(const s16x8*)(wkb + wbase + s*32 + g*8);
            ak = mfma32(A[s], Bk, ak);
            s16x8 Bv = *(const s16x8*)(wvb + wbase + s*32 + g*8);
            av = mfma32(A[s], Bv, av);
        }
        const int o = nt*16 + c;
        const float bqv = bq[o]*LOG2E, bkv = bk[o], bvv = bv[o];
        #pragma unroll
        for (int rr = 0; rr < 4; ++rr) {
            qt[baseqk[rr] + (size_t)o*HDP] = f2bf(aq[rr] + bqv);
            kt[baseqk[rr] + (size_t)o*HDP] = f2bf(ak[rr] + bkv);
            vb[basev[rr] + o]              = f2bf(av[rr] + bvv);
        }
    }
}

// ---------------- Pass 1 (fused): Z + quad-major Vz ----------------------
// R21: m-tile 128 (960 blocks) — 16 E-chains/wave, each kb load feeds 16
// MFMAs (2x reuse), total kt L2 reads halved; ping-pong kb sets (no
// rotation movs). Tail produces vzt for 128 m (coalesced).
__global__ __launch_bounds__(256, 3)
void zinv_kernel(const unsigned short* __restrict__ qt,
                 const unsigned short* __restrict__ kt,
                 const unsigned short* __restrict__ vb,
                 unsigned short* __restrict__ vzt)
{
    __shared__ float zred[4][128];
    // bijective swizzle: grid 960 (%8==0), chunk 120 per XCD
    const int blk  = ((int)blockIdx.x & 7) * (NBH*(NN/128)/8) + ((int)blockIdx.x >> 3);
    const int bh   = blk / (NN/128);
    const int m0   = (blk % (NN/128)) * 128;
    const int tid  = threadIdx.x;
    const int wv   = tid >> 6;
    const int lane = tid & 63;
    const int g = lane >> 4, c = lane & 15;

    s16x8 qa[8];
    #pragma unroll
    for (int ms = 0; ms < 8; ++ms)
        qa[ms] = *(const s16x8*)(qt + ((size_t)bh*NN + m0 + ms*16 + c)*HDP + g*8);

    const f32x4 zero4 = {0.f, 0.f, 0.f, 0.f};
    f32x4 z[8];
    #pragma unroll
    for (int ms = 0; ms < 8; ++ms) z[ms] = zero4;

    const unsigned short* kbase = kt + (size_t)bh*NN*HDP;
    const int nbeg = wv * (NN/4);          // 960 n per wave = 30 steps of 32

    #define ZLOAD(K0, K1, NNV)                                                 \
        K0 = *(const s16x8*)(kbase + (size_t)((NNV) +      c)*HDP + g*8);      \
        K1 = *(const s16x8*)(kbase + (size_t)((NNV) + 16 + c)*HDP + g*8);

    #define ZSTEP(K0, K1)                                                      \
        _Pragma("unroll")                                                      \
        for (int ms = 0; ms < 8; ++ms) {                                       \
            f32x4 e0 = mfma32(qa[ms], K0, zero4);                              \
            f32x4 e1 = mfma32(qa[ms], K1, zero4);                              \
            _Pragma("unroll")                                                  \
            for (int rr = 0; rr < 4; ++rr)                                     \
                z[ms][rr] += exp2fast(e0[rr]) + exp2fast(e1[rr]);              \
        }

    s16x8 kA0, kA1, kB0, kB1;
    ZLOAD(kA0, kA1, nbeg)                            // step 0
    for (int k = 0; k < 28; k += 2) {
        ZLOAD(kB0, kB1, nbeg + (k+1)*32)             // prefetch k+1
        ZSTEP(kA0, kA1)                              // compute k
        ZLOAD(kA0, kA1, nbeg + (k+2)*32)             // prefetch k+2
        ZSTEP(kB0, kB1)                              // compute k+1
    }
    ZLOAD(kB0, kB1, nbeg + 29*32)
    ZSTEP(kA0, kA1)                                  // step 28
    ZSTEP(kB0, kB1)                                  // step 29
    #undef ZLOAD
    #undef ZSTEP

    #pragma unroll
    for (int ms = 0; ms < 8; ++ms) {
        #pragma unroll
        for (int rr = 0; rr < 4; ++rr) {
            float v = z[ms][rr];
            v += __shfl_xor(v, 1);
            v += __shfl_xor(v, 2);
            v += __shfl_xor(v, 4);
            v += __shfl_xor(v, 8);
            if (c == 0) zred[wv][ms*16 + g*4 + rr] = v;
        }
    }
    __syncthreads();
    if (tid < 128) {
        float s = zred[0][tid] + zred[1][tid] + zred[2][tid] + zred[3][tid];
        zred[0][tid] = 1.0f / s;      // same-thread RMW of own slot: safe
    }
    __syncthreads();

    // fused Vz: thread = (dp = tid&31, oct = tid>>5); 16 m per thread
    {
        const int dp   = tid & 31;
        const int oct  = tid >> 5;     // 0..7
        const int mloc = oct * 16;
        unsigned short pv[16];
        if (dp < HD) {
            const unsigned short* src = vb + ((size_t)bh*HD + dp)*NN + m0 + mloc;
            s16x8 raw0 = *(const s16x8*)src;         // 16B contiguous
            s16x8 raw1 = *(const s16x8*)(src + 8);
            #pragma unroll
            for (int j = 0; j < 8; ++j) {
                pv[j]   = f2bf(bf2f((unsigned short)raw0[j]) * zred[0][mloc + j]);
                pv[j+8] = f2bf(bf2f((unsigned short)raw1[j]) * zred[0][mloc + 8 + j]);
            }
        } else {
            #pragma unroll
            for (int j = 0; j < 16; ++j) pv[j] = 0;
        }
        unsigned short* dst = vzt + (size_t)bh*HDP*NN
                                  + (size_t)((m0 + mloc)/4)*(HDP*4) + dp*4;
        #pragma unroll
        for (int qq = 0; qq < 4; ++qq) {
            s16x4 o;
            o[0]=(short)pv[qq*4+0]; o[1]=(short)pv[qq*4+1];
            o[2]=(short)pv[qq*4+2]; o[3]=(short)pv[qq*4+3];
            *(s16x4*)(dst + (size_t)qq*(HDP*4)) = o;
        }
    }
}

// ---------------- Pass 2: out = Vz * exp2(Q^T K) (R20-exact, passing) ----
__global__ __launch_bounds__(256, 3)
void attn_out_kernel(const unsigned short* __restrict__ qt,
                     const unsigned short* __restrict__ kt,
                     const unsigned short* __restrict__ vzt,
                     float* __restrict__ y)
{
    __shared__ float red[3][32][64];   // 24 KB
    const int blk  = ((int)blockIdx.x & 7) * (NBH*(NN/64)/8) + ((int)blockIdx.x >> 3);
    const int bh   = blk / (NN/64);
    const int n0   = (blk % (NN/64)) * 64;
    const int tid  = threadIdx.x;
    const int wv   = tid >> 6;
    const int lane = tid & 63;
    const int g = lane >> 4, c = lane & 15;
    const int b = bh >> 3, nh = bh & 7;

    const f32x4 zero4 = {0.f, 0.f, 0.f, 0.f};
    const unsigned short* qb  = qt  + (size_t)bh*NN*HDP;
    const unsigned short* kbp = kt  + (size_t)bh*NN*HDP;
    const unsigned short* vp  = vzt + (size_t)bh*HDP*NN;

    s16x8 kb[4];
    #pragma unroll
    for (int ns = 0; ns < 4; ++ns)
        kb[ns] = *(const s16x8*)(kbp + ((size_t)(n0 + ns*16 + c))*HDP + g*8);

    f32x4 acc[2][4];
    #pragma unroll
    for (int ds = 0; ds < 2; ++ds)
        #pragma unroll
        for (int ns = 0; ns < 4; ++ns) acc[ds][ns] = zero4;

    const int mbeg = wv * (NN/4);          // 960 m per wave = 15 steps of 64

    #define LOAD_FRAGS(QA, VA, MM)                                            \
        _Pragma("unroll")                                                     \
        for (int j = 0; j < 4; ++j)                                           \
            QA[j] = *(const s16x8*)(qb + ((size_t)((MM) + j*16 + c))*HDP + g*8); \
        _Pragma("unroll")                                                     \
        for (int ds = 0; ds < 2; ++ds)                                        \
            _Pragma("unroll")                                                 \
            for (int j = 0; j < 4; ++j)                                       \
                VA[ds][j] = *(const s16x4*)(vp + (size_t)(((MM) >> 2) + j*4 + g)*(HDP*4) \
                                               + (ds*16 + c)*4);

    #define COMPUTE_STEP(QA, VA)                                              \
        _Pragma("unroll")                                                     \
        for (int ns = 0; ns < 4; ++ns) {                                      \
            f32x4 e0 = mfma32(QA[0], kb[ns], zero4);                          \
            f32x4 e1 = mfma32(QA[1], kb[ns], zero4);                          \
            f32x4 e2 = mfma32(QA[2], kb[ns], zero4);                          \
            f32x4 e3 = mfma32(QA[3], kb[ns], zero4);                          \
            s16x8 P01 = cat44(exp4_pack(e0), exp4_pack(e1));                  \
            s16x8 P23 = cat44(exp4_pack(e2), exp4_pack(e3));                  \
            acc[0][ns] = mfma32(cat44(VA[0][0], VA[0][1]), P01, acc[0][ns]);  \
            acc[0][ns] = mfma32(cat44(VA[0][2], VA[0][3]), P23, acc[0][ns]);  \
            acc[1][ns] = mfma32(cat44(VA[1][0], VA[1][1]), P01, acc[1][ns]);  \
            acc[1][ns] = mfma32(cat44(VA[1][2], VA[1][3]), P23, acc[1][ns]);  \
        }

    s16x8 qaA[4], qaB[4];
    s16x4 vaA[2][4], vaB[2][4];
    LOAD_FRAGS(qaA, vaA, mbeg)                       // step 0

    for (int k = 0; k < 14; k += 2) {
        const int mB = mbeg + (k+1)*64;
        const int mA = mbeg + (k+2)*64;
        LOAD_FRAGS(qaB, vaB, mB)                     // prefetch step k+1
        COMPUTE_STEP(qaA, vaA)                       // compute step k
        LOAD_FRAGS(qaA, vaA, mA)                     // prefetch step k+2
        COMPUTE_STEP(qaB, vaB)                       // compute step k+1
    }
    COMPUTE_STEP(qaA, vaA)                           // epilogue: step 14

    #undef LOAD_FRAGS
    #undef COMPUTE_STEP

    float* af = (float*)acc;   // 32 contiguous f32
    if (wv > 0) {
        #pragma unroll
        for (int j = 0; j < 32; ++j) red[wv-1][j][lane] = af[j];
    }
    __syncthreads();
    if (wv == 0) {
        #pragma unroll
        for (int j = 0; j < 32; ++j)
            af[j] += red[0][j][lane] + red[1][j][lane] + red[2][j][lane];
        float* yb = y + (size_t)b * CC * HH * WW;
        #pragma unroll
        for (int ds = 0; ds < 2; ++ds) {
            #pragma unroll
            for (int ns = 0; ns < 4; ++ns) {
                #pragma unroll
                for (int rr = 0; rr < 4; ++rr) {
                    int dd = ds*16 + g*4 + rr;
                    if (dd < HD)
                        yb[((size_t)(dd*NH_ + nh))*NN + n0 + ns*16 + c] = acc[ds][ns][rr];
                }
            }
        }
    }
}

extern "C" void kernel_launch(void* const* d_in, const int* in_sizes, int n_in,
                              void* d_out, int out_size, void* d_ws, size_t ws_size,
                              hipStream_t stream)
{
    const float* x  = (const float*)d_in[0];
    const float* Wq = (const float*)d_in[1];
    const float* bq = (const float*)d_in[2];
    const float* Wk = (const float*)d_in[3];
    const float* bk = (const float*)d_in[4];
    const float* Wv = (const float*)d_in[5];
    const float* bv = (const float*)d_in[6];
    float* y = (float*)d_out;

    const size_t QT_E = (size_t)NBH * NN * HDP;      // 3,932,160 bf16
    unsigned short* qt  = (unsigned short*)d_ws;
    unsigned short* kt  = qt + QT_E;
    unsigned short* vb  = kt + QT_E;
    unsigned short* vzt = vb + (size_t)NBH * HD * NN;
    unsigned short* wqb = vzt + QT_E;
    unsigned short* wkb = wqb + WW*WW;
    unsigned short* wvb = wkb + WW*WW;               // total ~28.7 MB

    hipMemsetAsync(qt, 0, 2 * QT_E * sizeof(unsigned short), stream);

    wprep_kernel<<<dim3((WW*WW + 255)/256), dim3(256), 0, stream>>>(
        Wq, Wk, Wv, wqb, wkb, wvb);
    proj_mfma_kernel<<<dim3(BB*ROWS/32), dim3(256), 0, stream>>>(
        x, wqb, wkb, wvb, bq, bk, bv, qt, kt, vb);
    zinv_kernel<<<dim3(NBH*(NN/128)), dim3(256), 0, stream>>>(qt, kt, vb, vzt);
    attn_out_kernel<<<dim3(NBH*(NN/64)), dim3(256), 0, stream>>>(qt, kt, vzt, y);
}

// Round 22
// 170.123 us; speedup vs baseline: 1.1864x; 1.1864x over previous
//
#include <hip/hip_runtime.h>
#include <hip/hip_bf16.h>
#include <math.h>

#define BB   4
#define CC   32
#define HH   120
#define WW   160
#define NH_  8
#define HD   20
#define HDP  32            // head dim padded to 32 (zeros) for K=32 MFMA
#define NN   3840          // sequence length (C*H)
#define ROWS 3840
#define NBH  32            // B * NH
#define LOG2E 1.44269504088896f

typedef float f32x4 __attribute__((ext_vector_type(4)));
typedef short s16x8 __attribute__((ext_vector_type(8)));
typedef short s16x4 __attribute__((ext_vector_type(4)));

static __device__ __forceinline__ unsigned short f2bf(float x) {
    return __builtin_bit_cast(unsigned short, __float2bfloat16(x));
}
static __device__ __forceinline__ float bf2f(unsigned short u) {
    unsigned v = ((unsigned)u) << 16;
    return __builtin_bit_cast(float, v);
}
static __device__ __forceinline__ float exp2fast(float x) {
#if defined(__has_builtin) && __has_builtin(__builtin_amdgcn_exp2f)
    return __builtin_amdgcn_exp2f(x);
#else
    float r; asm("v_exp_f32 %0, %1" : "=v"(r) : "v"(x)); return r;
#endif
}

// exp2 four lanes then pack to bf16 by TRUNCATION (validated R18-R21:
// absmax 0.0176 < 0.0306). BUILTIN-ONLY pack — perm path validated
// R5/R9-R21. Do NOT use the cvt_pk inline-asm variant (R7/R8 corruption).
static __device__ __forceinline__ s16x4 exp4_pack(f32x4 e) {
    unsigned u0 = __builtin_bit_cast(unsigned, exp2fast(e[0]));
    unsigned u1 = __builtin_bit_cast(unsigned, exp2fast(e[1]));
    unsigned u2 = __builtin_bit_cast(unsigned, exp2fast(e[2]));
    unsigned u3 = __builtin_bit_cast(unsigned, exp2fast(e[3]));
    uint2 w;
#if defined(__has_builtin) && __has_builtin(__builtin_amdgcn_perm)
    w.x = __builtin_amdgcn_perm(u1, u0, 0x07060302u);
    w.y = __builtin_amdgcn_perm(u3, u2, 0x07060302u);
#else
    w.x = (u0 >> 16) | (u1 & 0xffff0000u);
    w.y = (u2 >> 16) | (u3 & 0xffff0000u);
#endif
    return __builtin_bit_cast(s16x4, w);
}

static __device__ __forceinline__ f32x4 mfma32(s16x8 a, s16x8 b, f32x4 c) {
    return __builtin_amdgcn_mfma_f32_16x16x32_bf16(a, b, c, 0, 0, 0);
}
// concat two s16x4 into a K=32 fragment half-pair (register pairing, no ops)
static __device__ __forceinline__ s16x8 cat44(s16x4 a, s16x4 b) {
    s16x8 r;
    r[0]=a[0]; r[1]=a[1]; r[2]=a[2]; r[3]=a[3];
    r[4]=b[0]; r[5]=b[1]; r[6]=b[2]; r[7]=b[3];
    return r;
}

// ---------------- W prep: f32 -> bf16 [o][k]; Wq pre-scaled by log2(e) ----
__global__ __launch_bounds__(256)
void wprep_kernel(const float* __restrict__ Wq, const float* __restrict__ Wk,
                  const float* __restrict__ Wv,
                  unsigned short* __restrict__ wqb, unsigned short* __restrict__ wkb,
                  unsigned short* __restrict__ wvb)
{
    int i = blockIdx.x*256 + threadIdx.x;
    if (i < WW*WW) {
        wqb[i] = f2bf(Wq[i] * LOG2E);
        wkb[i] = f2bf(Wk[i]);
        wvb[i] = f2bf(Wv[i]);
    }
}

// ---------------- Projection via MFMA (no LDS), R18 regrid (unchanged) ---
__global__ __launch_bounds__(256)
void proj_mfma_kernel(const float* __restrict__ x,
                      const unsigned short* __restrict__ wqb,
                      const unsigned short* __restrict__ wkb,
                      const unsigned short* __restrict__ wvb,
                      const float* __restrict__ bq, const float* __restrict__ bk,
                      const float* __restrict__ bv,
                      unsigned short* __restrict__ qt, unsigned short* __restrict__ kt,
                      unsigned short* __restrict__ vb)
{
    const int tid  = threadIdx.x;
    const int wv   = tid >> 6;
    const int lane = tid & 63;
    const int g = lane >> 4, c = lane & 15;
    const int r0 = blockIdx.x*32 + (wv & 1)*16;   // wave's 16-row tile
    const int ch = wv >> 1;                        // col half: tiles ch*5..ch*5+4

    s16x8 A[5];
    const float* xrow = x + (size_t)(r0 + c)*WW;
    #pragma unroll
    for (int s = 0; s < 5; ++s) {
        float4 v0 = *(const float4*)(xrow + s*32 + g*8);
        float4 v1 = *(const float4*)(xrow + s*32 + g*8 + 4);
        s16x8 a;
        a[0]=(short)f2bf(v0.x); a[1]=(short)f2bf(v0.y);
        a[2]=(short)f2bf(v0.z); a[3]=(short)f2bf(v0.w);
        a[4]=(short)f2bf(v1.x); a[5]=(short)f2bf(v1.y);
        a[6]=(short)f2bf(v1.z); a[7]=(short)f2bf(v1.w);
        A[s] = a;
    }

    size_t baseqk[4], basev[4];
    #pragma unroll
    for (int rr = 0; rr < 4; ++rr) {
        int R  = r0 + g*4 + rr;
        int b  = R / ROWS;
        int r  = R % ROWS;
        int nh = r / 480;
        int rm = r % 480;
        int d  = rm / 24;
        int n1 = rm % 24;
        int bh = b*NH_ + nh;
        baseqk[rr] = ((size_t)bh*NN + n1*160)*HDP + d;
        basev[rr]  = ((size_t)bh*HD + d)*NN + n1*160;
    }

    const f32x4 zero4 = {0.f, 0.f, 0.f, 0.f};
    for (int nt = ch*5; nt < ch*5 + 5; ++nt) {
        const size_t wbase = (size_t)(nt*16 + c)*WW;
        f32x4 aq = zero4, ak = zero4, av = zero4;
        #pragma unroll
        for (int s = 0; s < 5; ++s) {
            s16x8 Bq = *(const s16x8*)(wqb + wbase + s*32 + g*8);
            aq = mfma32(A[s], Bq, aq);
            s16x8 Bk = *(const s16x8*)(wkb + wbase + s*32 + g*8);
            ak = mfma32(A[s], Bk, ak);
            s16x8 Bv = *(const s16x8*)(wvb + wbase + s*32 + g*8);
            av = mfma32(A[s], Bv, av);
        }
        const int o = nt*16 + c;
        const float bqv = bq[o]*LOG2E, bkv = bk[o], bvv = bv[o];
        #pragma unroll
        for (int rr = 0; rr < 4; ++rr) {
            qt[baseqk[rr] + (size_t)o*HDP] = f2bf(aq[rr] + bqv);
            kt[baseqk[rr] + (size_t)o*HDP] = f2bf(ak[rr] + bkv);
            vb[basev[rr] + o]              = f2bf(av[rr] + bvv);
        }
    }
}

// ---------------- Pass 1 (fused): Z + quad-major Vz ----------------------
// R22: REVERT to R20 shape (m-tile 64, lb(256,4), qa[4]/z[4], 1920 blocks,
// XCD swizzle) — R21's m-128 cut occupancy (84 VGPR, 25%) and regressed
// 68->95us. Only delta vs R20: ping-pong kb sets (no rotation movs).
__global__ __launch_bounds__(256, 4)
void zinv_kernel(const unsigned short* __restrict__ qt,
                 const unsigned short* __restrict__ kt,
                 const unsigned short* __restrict__ vb,
                 unsigned short* __restrict__ vzt)
{
    __shared__ float zred[4][64];
    const int blk  = ((int)blockIdx.x & 7) * (NBH*(NN/64)/8) + ((int)blockIdx.x >> 3);
    const int bh   = blk / (NN/64);
    const int m0   = (blk % (NN/64)) * 64;
    const int tid  = threadIdx.x;
    const int wv   = tid >> 6;
    const int lane = tid & 63;
    const int g = lane >> 4, c = lane & 15;

    s16x8 qa[4];
    #pragma unroll
    for (int ms = 0; ms < 4; ++ms)
        qa[ms] = *(const s16x8*)(qt + ((size_t)bh*NN + m0 + ms*16 + c)*HDP + g*8);

    const f32x4 zero4 = {0.f, 0.f, 0.f, 0.f};
    f32x4 z[4];
    #pragma unroll
    for (int ms = 0; ms < 4; ++ms) z[ms] = zero4;

    const unsigned short* kbase = kt + (size_t)bh*NN*HDP;
    const int nbeg = wv * (NN/4);          // 960 n per wave = 30 steps of 32

    #define ZLOAD(K0, K1, NNV)                                                 \
        K0 = *(const s16x8*)(kbase + (size_t)((NNV) +      c)*HDP + g*8);      \
        K1 = *(const s16x8*)(kbase + (size_t)((NNV) + 16 + c)*HDP + g*8);

    #define ZSTEP(K0, K1)                                                      \
        _Pragma("unroll")                                                      \
        for (int ms = 0; ms < 4; ++ms) {                                       \
            f32x4 e0 = mfma32(qa[ms], K0, zero4);                              \
            f32x4 e1 = mfma32(qa[ms], K1, zero4);                              \
            _Pragma("unroll")                                                  \
            for (int rr = 0; rr < 4; ++rr)                                     \
                z[ms][rr] += exp2fast(e0[rr]) + exp2fast(e1[rr]);              \
        }

    s16x8 kA0, kA1, kB0, kB1;
    ZLOAD(kA0, kA1, nbeg)                            // step 0
    for (int k = 0; k < 28; k += 2) {
        ZLOAD(kB0, kB1, nbeg + (k+1)*32)             // prefetch k+1
        ZSTEP(kA0, kA1)                              // compute k
        ZLOAD(kA0, kA1, nbeg + (k+2)*32)             // prefetch k+2
        ZSTEP(kB0, kB1)                              // compute k+1
    }
    ZLOAD(kB0, kB1, nbeg + 29*32)
    ZSTEP(kA0, kA1)                                  // step 28
    ZSTEP(kB0, kB1)                                  // step 29
    #undef ZLOAD
    #undef ZSTEP

    #pragma unroll
    for (int ms = 0; ms < 4; ++ms) {
        #pragma unroll
        for (int rr = 0; rr < 4; ++rr) {
            float v = z[ms][rr];
            v += __shfl_xor(v, 1);
            v += __shfl_xor(v, 2);
            v += __shfl_xor(v, 4);
            v += __shfl_xor(v, 8);
            if (c == 0) zred[wv][ms*16 + g*4 + rr] = v;
        }
    }
    __syncthreads();
    if (tid < 64) {
        float s = zred[0][tid] + zred[1][tid] + zred[2][tid] + zred[3][tid];
        zred[0][tid] = 1.0f / s;      // same-thread RMW of own slot: safe
    }
    __syncthreads();

    // fused Vz: thread = (dp = tid&31, half = tid>>5); m-sub = half*8
    {
        const int dp   = tid & 31;
        const int half = tid >> 5;
        const int mloc = half * 8;
        unsigned short pv[8];
        if (dp < HD) {
            const unsigned short* src = vb + ((size_t)bh*HD + dp)*NN + m0 + mloc;
            s16x8 raw = *(const s16x8*)src;    // 16B contiguous, aligned
            #pragma unroll
            for (int j = 0; j < 8; ++j)
                pv[j] = f2bf(bf2f((unsigned short)raw[j]) * zred[0][mloc + j]);
        } else {
            #pragma unroll
            for (int j = 0; j < 8; ++j) pv[j] = 0;
        }
        unsigned short* dst = vzt + (size_t)bh*HDP*NN
                                  + (size_t)(m0/4 + half*2)*(HDP*4) + dp*4;
        s16x4 o0, o1;
        o0[0]=(short)pv[0]; o0[1]=(short)pv[1]; o0[2]=(short)pv[2]; o0[3]=(short)pv[3];
        o1[0]=(short)pv[4]; o1[1]=(short)pv[5]; o1[2]=(short)pv[6]; o1[3]=(short)pv[7];
        *(s16x4*)dst = o0;
        *(s16x4*)(dst + HDP*4) = o1;
    }
}

// ---------------- Pass 2: out = Vz * exp2(Q^T K) (R20-exact, passing) ----
__global__ __launch_bounds__(256, 3)
void attn_out_kernel(const unsigned short* __restrict__ qt,
                     const unsigned short* __restrict__ kt,
                     const unsigned short* __restrict__ vzt,
                     float* __restrict__ y)
{
    __shared__ float red[3][32][64];   // 24 KB
    const int blk  = ((int)blockIdx.x & 7) * (NBH*(NN/64)/8) + ((int)blockIdx.x >> 3);
    const int bh   = blk / (NN/64);
    const int n0   = (blk % (NN/64)) * 64;
    const int tid  = threadIdx.x;
    const int wv   = tid >> 6;
    const int lane = tid & 63;
    const int g = lane >> 4, c = lane & 15;
    const int b = bh >> 3, nh = bh & 7;

    const f32x4 zero4 = {0.f, 0.f, 0.f, 0.f};
    const unsigned short* qb  = qt  + (size_t)bh*NN*HDP;
    const unsigned short* kbp = kt  + (size_t)bh*NN*HDP;
    const unsigned short* vp  = vzt + (size_t)bh*HDP*NN;

    s16x8 kb[4];
    #pragma unroll
    for (int ns = 0; ns < 4; ++ns)
        kb[ns] = *(const s16x8*)(kbp + ((size_t)(n0 + ns*16 + c))*HDP + g*8);

    f32x4 acc[2][4];
    #pragma unroll
    for (int ds = 0; ds < 2; ++ds)
        #pragma unroll
        for (int ns = 0; ns < 4; ++ns) acc[ds][ns] = zero4;

    const int mbeg = wv * (NN/4);          // 960 m per wave = 15 steps of 64

    #define LOAD_FRAGS(QA, VA, MM)                                            \
        _Pragma("unroll")                                                     \
        for (int j = 0; j < 4; ++j)                                           \
            QA[j] = *(const s16x8*)(qb + ((size_t)((MM) + j*16 + c))*HDP + g*8); \
        _Pragma("unroll")                                                     \
        for (int ds = 0; ds < 2; ++ds)                                        \
            _Pragma("unroll")                                                 \
            for (int j = 0; j < 4; ++j)                                       \
                VA[ds][j] = *(const s16x4*)(vp + (size_t)(((MM) >> 2) + j*4 + g)*(HDP*4) \
                                               + (ds*16 + c)*4);

    #define COMPUTE_STEP(QA, VA)                                              \
        _Pragma("unroll")                                                     \
        for (int ns = 0; ns < 4; ++ns) {                                      \
            f32x4 e0 = mfma32(QA[0], kb[ns], zero4);                          \
            f32x4 e1 = mfma32(QA[1], kb[ns], zero4);                          \
            f32x4 e2 = mfma32(QA[2], kb[ns], zero4);                          \
            f32x4 e3 = mfma32(QA[3], kb[ns], zero4);                          \
            s16x8 P01 = cat44(exp4_pack(e0), exp4_pack(e1));                  \
            s16x8 P23 = cat44(exp4_pack(e2), exp4_pack(e3));                  \
            acc[0][ns] = mfma32(cat44(VA[0][0], VA[0][1]), P01, acc[0][ns]);  \
            acc[0][ns] = mfma32(cat44(VA[0][2], VA[0][3]), P23, acc[0][ns]);  \
            acc[1][ns] = mfma32(cat44(VA[1][0], VA[1][1]), P01, acc[1][ns]);  \
            acc[1][ns] = mfma32(cat44(VA[1][2], VA[1][3]), P23, acc[1][ns]);  \
        }

    s16x8 qaA[4], qaB[4];
    s16x4 vaA[2][4], vaB[2][4];
    LOAD_FRAGS(qaA, vaA, mbeg)                       // step 0

    for (int k = 0; k < 14; k += 2) {
        const int mB = mbeg + (k+1)*64;
        const int mA = mbeg + (k+2)*64;
        LOAD_FRAGS(qaB, vaB, mB)                     // prefetch step k+1
        COMPUTE_STEP(qaA, vaA)                       // compute step k
        LOAD_FRAGS(qaA, vaA, mA)                     // prefetch step k+2
        COMPUTE_STEP(qaB, vaB)                       // compute step k+1
    }
    COMPUTE_STEP(qaA, vaA)                           // epilogue: step 14

    #undef LOAD_FRAGS
    #undef COMPUTE_STEP

    float* af = (float*)acc;   // 32 contiguous f32
    if (wv > 0) {
        #pragma unroll
        for (int j = 0; j < 32; ++j) red[wv-1][j][lane] = af[j];
    }
    __syncthreads();
    if (wv == 0) {
        #pragma unroll
        for (int j = 0; j < 32; ++j)
            af[j] += red[0][j][lane] + red[1][j][lane] + red[2][j][lane];
        float* yb = y + (size_t)b * CC * HH * WW;
        #pragma unroll
        for (int ds = 0; ds < 2; ++ds) {
            #pragma unroll
            for (int ns = 0; ns < 4; ++ns) {
                #pragma unroll
                for (int rr = 0; rr < 4; ++rr) {
                    int dd = ds*16 + g*4 + rr;
                    if (dd < HD)
                        yb[((size_t)(dd*NH_ + nh))*NN + n0 + ns*16 + c] = acc[ds][ns][rr];
                }
            }
        }
    }
}

extern "C" void kernel_launch(void* const* d_in, const int* in_sizes, int n_in,
                              void* d_out, int out_size, void* d_ws, size_t ws_size,
                              hipStream_t stream)
{
    const float* x  = (const float*)d_in[0];
    const float* Wq = (const float*)d_in[1];
    const float* bq = (const float*)d_in[2];
    const float* Wk = (const float*)d_in[3];
    const float* bk = (const float*)d_in[4];
    const float* Wv = (const float*)d_in[5];
    const float* bv = (const float*)d_in[6];
    float* y = (float*)d_out;

    const size_t QT_E = (size_t)NBH * NN * HDP;      // 3,932,160 bf16
    unsigned short* qt  = (unsigned short*)d_ws;
    unsigned short* kt  = qt + QT_E;
    unsigned short* vb  = kt + QT_E;
    unsigned short* vzt = vb + (size_t)NBH * HD * NN;
    unsigned short* wqb = vzt + QT_E;
    unsigned short* wkb = wqb + WW*WW;
    unsigned short* wvb = wkb + WW*WW;               // total ~28.7 MB

    hipMemsetAsync(qt, 0, 2 * QT_E * sizeof(unsigned short), stream);

    wprep_kernel<<<dim3((WW*WW + 255)/256), dim3(256), 0, stream>>>(
        Wq, Wk, Wv, wqb, wkb, wvb);
    proj_mfma_kernel<<<dim3(BB*ROWS/32), dim3(256), 0, stream>>>(
        x, wqb, wkb, wvb, bq, bk, bv, qt, kt, vb);
    zinv_kernel<<<dim3(NBH*(NN/64)), dim3(256), 0, stream>>>(qt, kt, vb, vzt);
    attn_out_kernel<<<dim3(NBH*(NN/64)), dim3(256), 0, stream>>>(qt, kt, vzt, y);
}